// Round 2
// baseline (14153.954 us; speedup 1.0000x reference)
//
#include <hip/hip_runtime.h>

typedef unsigned short u16;
typedef short bf16x8 __attribute__((ext_vector_type(8)));
typedef _Float16 f16x8 __attribute__((ext_vector_type(8)));
typedef _Float16 h2 __attribute__((ext_vector_type(2)));
typedef float f32x4 __attribute__((ext_vector_type(4)));

struct __align__(8) u16x4s { u16 x, y, z, w; };

__device__ __forceinline__ u16 f2bf(float f) {
    union { float f; unsigned u; } v; v.f = f;
    unsigned u = v.u;
    unsigned r = u + 0x7fffu + ((u >> 16) & 1u);
    return (u16)(r >> 16);
}
__device__ __forceinline__ u16 f2h(float f) {
    union { _Float16 h; u16 u; } v; v.h = (_Float16)f; return v.u;
}
__device__ __forceinline__ float sigmoidf(float x) { return 1.0f / (1.0f + expf(-x)); }

__device__ __forceinline__ h2 bch2(unsigned u) { return __builtin_bit_cast(h2, u); }

#if __has_builtin(__builtin_amdgcn_fdot2)
__device__ __forceinline__ float fdot2(h2 a, h2 b, float c) {
    return __builtin_amdgcn_fdot2(a, b, c, false);
}
#else
__device__ __forceinline__ float fdot2(h2 a, h2 b, float c) {
    return c + (float)a.x * (float)b.x + (float)a.y * (float)b.y;  // v_fma_mix
}
#endif

// 8 f16 MACs with 4 independent accumulator chains
__device__ __forceinline__ void dot8(uint4 w, uint4 s,
                                     float& a0, float& a1, float& a2, float& a3) {
    a0 = fdot2(bch2(w.x), bch2(s.x), a0);
    a1 = fdot2(bch2(w.y), bch2(s.y), a1);
    a2 = fdot2(bch2(w.z), bch2(s.z), a2);
    a3 = fdot2(bch2(w.w), bch2(s.w), a3);
}

#define GLOAD_LDS16(g, l) __builtin_amdgcn_global_load_lds( \
    (const __attribute__((address_space(1))) unsigned int*)(g), \
    (__attribute__((address_space(3))) unsigned int*)(l), 16, 0, 0)

// ---------------------------------------------------------------------------
// bf16 GEMM: C(M,N) = A(M,K) * Bt(N,K)^T
// mode 0: Cf[m*2048+n] = acc + b_ih[n] + b_hh[n]       (xgates, [t*32+b][2048])
// mode 1: Cb[m*N+n] = f16(acc)                          (srcWp, f16 output)
// ---------------------------------------------------------------------------
__global__ __launch_bounds__(256) void gemm_bt(
    const u16* __restrict__ A, const u16* __restrict__ Bt,
    float* __restrict__ Cf, u16* __restrict__ Cb,
    const float* __restrict__ bias1, const float* __restrict__ bias2,
    int M, int N, int K, int mode)
{
    __shared__ __align__(16) u16 As[128 * 64];
    __shared__ __align__(16) u16 Bs[128 * 64];
    int tid = threadIdx.x;
    int w = tid >> 6, lane = tid & 63;
    int wm = w >> 1, wn = w & 1;
    int m0 = blockIdx.y * 128, n0 = blockIdx.x * 128;

    f32x4 acc[4][4];
#pragma unroll
    for (int i = 0; i < 4; i++)
#pragma unroll
        for (int j = 0; j < 4; j++)
#pragma unroll
            for (int r = 0; r < 4; r++) acc[i][j][r] = 0.0f;

    int lrow = lane >> 3;
    int lcol = (lane & 7) * 8;

    for (int k0 = 0; k0 < K; k0 += 64) {
#pragma unroll
        for (int i = 0; i < 4; i++) {
            int li = i * 4 + w;
            int row = li * 8 + lrow;
            GLOAD_LDS16(A + (size_t)(m0 + row) * K + k0 + lcol, As + li * 512);
            GLOAD_LDS16(Bt + (size_t)(n0 + row) * K + k0 + lcol, Bs + li * 512);
        }
        __syncthreads();
        int lm = lane & 15;
#pragma unroll
        for (int kk = 0; kk < 2; kk++) {
            int lk = kk * 32 + (lane >> 4) * 8;
            bf16x8 af[4], bfr[4];
#pragma unroll
            for (int mt = 0; mt < 4; mt++)
                af[mt] = *(const bf16x8*)(As + (wm * 64 + mt * 16 + lm) * 64 + lk);
#pragma unroll
            for (int nt = 0; nt < 4; nt++)
                bfr[nt] = *(const bf16x8*)(Bs + (wn * 64 + nt * 16 + lm) * 64 + lk);
#pragma unroll
            for (int mt = 0; mt < 4; mt++)
#pragma unroll
                for (int nt = 0; nt < 4; nt++)
                    acc[mt][nt] = __builtin_amdgcn_mfma_f32_16x16x32_bf16(
                        af[mt], bfr[nt], acc[mt][nt], 0, 0, 0);
        }
        __syncthreads();
    }

    int col = lane & 15, rowq = (lane >> 4) * 4;
#pragma unroll
    for (int mt = 0; mt < 4; mt++) {
#pragma unroll
        for (int nt = 0; nt < 4; nt++) {
            f32x4 v = acc[mt][nt];
            int gn = n0 + wn * 64 + nt * 16 + col;
            int gmb = m0 + wm * 64 + mt * 16 + rowq;
#pragma unroll
            for (int r = 0; r < 4; r++) {
                int gm = gmb + r;
                float val = v[r];
                if (mode == 0) {
                    Cf[(size_t)gm * 2048 + gn] = val + bias1[gn] + bias2[gn];
                } else {
                    Cb[(size_t)gm * N + gn] = f2h(val);
                }
            }
        }
    }
}

// ---------------------------------------------------------------------------
// FC GEMM (f16): out[(b*64+t)*32000+n] = outs_h @ Wfc_h^T + bfc
// Both operands f16, staged via global_load_lds.
// ---------------------------------------------------------------------------
__global__ __launch_bounds__(256) void gemm_fc(
    const u16* __restrict__ A, const u16* __restrict__ Bt,
    float* __restrict__ out, const float* __restrict__ bfc)
{
    __shared__ __align__(16) u16 As[128 * 64];
    __shared__ __align__(16) u16 Bs[128 * 64];
    int tid = threadIdx.x;
    int w = tid >> 6, lane = tid & 63;
    int wm = w >> 1, wn = w & 1;
    int m0 = blockIdx.x * 128, n0 = blockIdx.y * 128;

    f32x4 acc[4][4];
#pragma unroll
    for (int i = 0; i < 4; i++)
#pragma unroll
        for (int j = 0; j < 4; j++)
#pragma unroll
            for (int r = 0; r < 4; r++) acc[i][j][r] = 0.0f;

    int lrow = lane >> 3;
    int lcol = (lane & 7) * 8;

    for (int k0 = 0; k0 < 512; k0 += 64) {
#pragma unroll
        for (int i = 0; i < 4; i++) {
            int li = i * 4 + w;
            int row = li * 8 + lrow;
            GLOAD_LDS16(A + (size_t)(m0 + row) * 512 + k0 + lcol, As + li * 512);
            GLOAD_LDS16(Bt + (size_t)(n0 + row) * 512 + k0 + lcol, Bs + li * 512);
        }
        __syncthreads();
        int lm = lane & 15;
#pragma unroll
        for (int kk = 0; kk < 2; kk++) {
            int lk = kk * 32 + (lane >> 4) * 8;
            f16x8 af[4], bfr[4];
#pragma unroll
            for (int mt = 0; mt < 4; mt++)
                af[mt] = *(const f16x8*)(As + (wm * 64 + mt * 16 + lm) * 64 + lk);
#pragma unroll
            for (int nt = 0; nt < 4; nt++)
                bfr[nt] = *(const f16x8*)(Bs + (wn * 64 + nt * 16 + lm) * 64 + lk);
#pragma unroll
            for (int mt = 0; mt < 4; mt++)
#pragma unroll
                for (int nt = 0; nt < 4; nt++)
                    acc[mt][nt] = __builtin_amdgcn_mfma_f32_16x16x32_f16(
                        af[mt], bfr[nt], acc[mt][nt], 0, 0, 0);
        }
        __syncthreads();
    }

    int col = lane & 15, rowq = (lane >> 4) * 4;
#pragma unroll
    for (int mt = 0; mt < 4; mt++) {
#pragma unroll
        for (int nt = 0; nt < 4; nt++) {
            f32x4 v = acc[mt][nt];
            int gn = n0 + wn * 64 + nt * 16 + col;
            int gmb = m0 + wm * 64 + mt * 16 + rowq;
#pragma unroll
            for (int r = 0; r < 4; r++) {
                int gm = gmb + r;
                int t = gm >> 5, b = gm & 31;
                out[((size_t)b * 64 + t) * 32000 + gn] = v[r] + bfc[gn];
            }
        }
    }
}

// ---------------------------------------------------------------------------
// Whole 64-step recurrence, batch-parallel: 32 blocks (one per b), 512 thr.
// Zero grid syncs. All state in LDS. f16 weights + v_dot2_f32_f16.
// ---------------------------------------------------------------------------
__global__ __launch_bounds__(512) void recur_b(
    const u16* __restrict__ Wcat_h,   // [2048][1024] f16 (gate-row major)
    const float* __restrict__ xg2,    // [t*32+b][2048] f32 (x-part + biases)
    const u16* __restrict__ srcWp_h,  // [b*64+s][512] f16
    const float* __restrict__ srcbias,// [b*64+s] f32
    const u16* __restrict__ srcT_h,   // [b][d=1024][s=64] f16
    const u16* __restrict__ Wah_h,    // [512][1536] f16
    const float* __restrict__ bah,
    const float* __restrict__ iff, const float* __restrict__ hid,
    u16* __restrict__ outs_h,         // [t*32+b][512] f16
    float* __restrict__ h_last, float* __restrict__ c_last,
    float* __restrict__ hh_last)
{
    __shared__ __align__(16) u16 sbf16[1024];   // [hhat | h] f16
    __shared__ __align__(16) u16 cat16[1536];   // [h | ctx] f16
    __shared__ __align__(16) u16 probs16[64];
    __shared__ float c_lds[512];
    __shared__ float gl[2048];
    __shared__ float sc_lds[64];

    int tid = threadIdx.x;
    int b = blockIdx.x;

    // init state
    {
        u16 hh = f2h(hid[tid]);
        sbf16[tid] = f2h(iff[tid]);
        sbf16[512 + tid] = hh;
        cat16[tid] = hh;
        c_lds[tid] = hid[512 + tid];
    }
    __syncthreads();

    int grp = tid >> 4, l16 = tid & 15;   // 32 groups of 16 (gates / Wah)
    int s8 = tid >> 3, l8 = tid & 7;      // 64 groups of 8 (scores / ctx)

    for (int t = 0; t < 64; t++) {
        // ---------------- Phase A: gates dot (rows grp*64 .. grp*64+63) -----
        {
            uint4 st[8];
#pragma unroll
            for (int sw = 0; sw < 8; sw++)
                st[sw] = *(const uint4*)(sbf16 + sw * 128 + l16 * 8);
            const u16* wbase = Wcat_h + (size_t)(grp * 64) * 1024 + l16 * 8;
#pragma unroll 2
            for (int i = 0; i < 64; i++) {
                const u16* wr = wbase + (size_t)i * 1024;
                float a0 = 0.f, a1 = 0.f, a2 = 0.f, a3 = 0.f;
#pragma unroll
                for (int sw = 0; sw < 8; sw++) {
                    uint4 wv = *(const uint4*)(wr + sw * 128);
                    dot8(wv, st[sw], a0, a1, a2, a3);
                }
                float a = (a0 + a1) + (a2 + a3);
                a += __shfl_xor(a, 1); a += __shfl_xor(a, 2);
                a += __shfl_xor(a, 4); a += __shfl_xor(a, 8);
                if (l16 == 0) gl[grp * 64 + i] = a;
            }
        }
        __syncthreads();

        // ---------------- Phase B: LSTM pointwise (unit j = tid) ------------
        {
            int j = tid;
            const float* xgp = xg2 + ((size_t)t * 32 + b) * 2048;
            float g0 = gl[j] + xgp[j];
            float g1 = gl[512 + j] + xgp[512 + j];
            float g2 = gl[1024 + j] + xgp[1024 + j];
            float g3 = gl[1536 + j] + xgp[1536 + j];
            float ig = sigmoidf(g0), fg = sigmoidf(g1);
            float gg = tanhf(g2), og = sigmoidf(g3);
            float cn = fg * c_lds[j] + ig * gg;
            c_lds[j] = cn;
            float hv = og * tanhf(cn);
            u16 h16 = f2h(hv);
            sbf16[512 + j] = h16;
            cat16[j] = h16;
            if (t == 63) {
                h_last[(size_t)b * 512 + j] = hv;
                c_last[(size_t)b * 512 + j] = cn;
            }
        }
        __syncthreads();

        // ---------------- Phase C: scores (8 lanes per s) -------------------
        {
            uint4 stc[8];
#pragma unroll
            for (int sw = 0; sw < 8; sw++)
                stc[sw] = *(const uint4*)(cat16 + sw * 64 + l8 * 8);
            const u16* wp = srcWp_h + ((size_t)b * 64 + s8) * 512 + l8 * 8;
            float a0 = 0.f, a1 = 0.f, a2 = 0.f, a3 = 0.f;
#pragma unroll
            for (int sw = 0; sw < 8; sw++) {
                uint4 wv = *(const uint4*)(wp + sw * 64);
                dot8(wv, stc[sw], a0, a1, a2, a3);
            }
            float a = (a0 + a1) + (a2 + a3);
            a += __shfl_xor(a, 1); a += __shfl_xor(a, 2); a += __shfl_xor(a, 4);
            if (l8 == 0)
                sc_lds[s8] = (a + srcbias[b * 64 + s8]) * 0.04419417382415922f;
        }
        __syncthreads();

        // ---------------- Phase D: softmax (wave 0) -------------------------
        if (tid < 64) {
            float sc = sc_lds[tid];
            float m = sc;
            for (int off = 32; off; off >>= 1) m = fmaxf(m, __shfl_xor(m, off));
            float e = expf(sc - m);
            float sum = e;
            for (int off = 32; off; off >>= 1) sum += __shfl_xor(sum, off);
            probs16[tid] = f2h(e / sum);
        }
        __syncthreads();

        // ---------------- Phase E: context (8 lanes per d) ------------------
        {
            uint4 pb = *(const uint4*)(probs16 + l8 * 8);
#pragma unroll 4
            for (int it = 0; it < 16; it++) {
                int d = it * 64 + s8;
                uint4 sv = *(const uint4*)(srcT_h + ((size_t)b * 1024 + d) * 64 + l8 * 8);
                float a0 = 0.f, a1 = 0.f, a2 = 0.f, a3 = 0.f;
                dot8(sv, pb, a0, a1, a2, a3);
                float a = (a0 + a1) + (a2 + a3);
                a += __shfl_xor(a, 1); a += __shfl_xor(a, 2); a += __shfl_xor(a, 4);
                if (l8 == 0) cat16[512 + d] = f2h(a);
            }
        }
        __syncthreads();

        // ---------------- Phase F: h_hat (16 lanes per row) -----------------
        {
            uint4 ct[12];
#pragma unroll
            for (int sw = 0; sw < 12; sw++)
                ct[sw] = *(const uint4*)(cat16 + sw * 128 + l16 * 8);
            const u16* wb = Wah_h + (size_t)(grp * 16) * 1536 + l16 * 8;
#pragma unroll 2
            for (int i = 0; i < 16; i++) {
                const u16* wr = wb + (size_t)i * 1536;
                float a0 = 0.f, a1 = 0.f, a2 = 0.f, a3 = 0.f;
#pragma unroll
                for (int sw = 0; sw < 12; sw++) {
                    uint4 wv = *(const uint4*)(wr + sw * 128);
                    dot8(wv, ct[sw], a0, a1, a2, a3);
                }
                float a = (a0 + a1) + (a2 + a3);
                a += __shfl_xor(a, 1); a += __shfl_xor(a, 2);
                a += __shfl_xor(a, 4); a += __shfl_xor(a, 8);
                if (l16 == 0) {
                    int j = grp * 16 + i;
                    float hv = tanhf(a + bah[j]);
                    u16 h16 = f2h(hv);
                    sbf16[j] = h16;
                    outs_h[((size_t)t * 32 + b) * 512 + j] = h16;
                    if (t == 63) hh_last[(size_t)b * 512 + j] = hv;
                }
            }
        }
        __syncthreads();
    }
}

// ---------------------------------------------------------------------------
// Prep kernels
// ---------------------------------------------------------------------------
__global__ void conv_f2b4(const float* __restrict__ in, u16* __restrict__ out, int n4) {
    int i = blockIdx.x * 256 + threadIdx.x;
    if (i < n4) {
        float4 v = ((const float4*)in)[i];
        u16x4s o; o.x = f2bf(v.x); o.y = f2bf(v.y); o.z = f2bf(v.z); o.w = f2bf(v.w);
        *(u16x4s*)(out + (size_t)i * 4) = o;
    }
}

__global__ void conv_f2h4(const float* __restrict__ in, u16* __restrict__ out, int n4) {
    int i = blockIdx.x * 256 + threadIdx.x;
    if (i < n4) {
        float4 v = ((const float4*)in)[i];
        u16x4s o; o.x = f2h(v.x); o.y = f2h(v.y); o.z = f2h(v.z); o.w = f2h(v.w);
        *(u16x4s*)(out + (size_t)i * 4) = o;
    }
}

__global__ void conv_wihx(const float* __restrict__ W_ih, u16* __restrict__ out) {
    int i = blockIdx.x * 256 + threadIdx.x;  // 2048 rows * 128 float4
    int r = i >> 7, k4 = i & 127;
    float4 v = ((const float4*)(W_ih + (size_t)r * 1024))[k4];
    u16x4s o; o.x = f2bf(v.x); o.y = f2bf(v.y); o.z = f2bf(v.z); o.w = f2bf(v.w);
    *(u16x4s*)(out + (size_t)r * 512 + k4 * 4) = o;
}

__global__ void conv_wcat_h(const float* __restrict__ W_ih, const float* __restrict__ W_hh,
                            u16* __restrict__ Wcat) {
    int i = blockIdx.x * 256 + threadIdx.x;  // 2048 * 256
    int r = i >> 8, c4 = i & 255;
    int col = c4 * 4;
    const float* src = (col < 512) ? (W_ih + (size_t)r * 1024 + 512 + col)
                                   : (W_hh + (size_t)r * 512 + (col - 512));
    float4 v = *(const float4*)src;
    u16x4s o; o.x = f2h(v.x); o.y = f2h(v.y); o.z = f2h(v.z); o.w = f2h(v.w);
    *(u16x4s*)(Wcat + (size_t)r * 1024 + col) = o;
}

__global__ void gather_emb(const int* __restrict__ trg, const float* __restrict__ emb,
                           u16* __restrict__ X) {
    int m = blockIdx.x;  // t*32+b
    int t = m >> 5, b = m & 31;
    int v = trg[b * 64 + t];
    const float4* e4 = (const float4*)(emb + (size_t)v * 512);
    int tid = threadIdx.x;  // 128
    float4 x = e4[tid];
    u16x4s o; o.x = f2bf(x.x); o.y = f2bf(x.y); o.z = f2bf(x.z); o.w = f2bf(x.w);
    *(u16x4s*)(X + (size_t)m * 512 + tid * 4) = o;
}

__global__ void transpose_wp(const float* __restrict__ Wp, u16* __restrict__ WpT) {
    int i = blockIdx.x * 256 + threadIdx.x;  // 512*1024
    int k = i >> 10, d = i & 1023;
    WpT[i] = f2bf(Wp[(size_t)d * 512 + k]);
}

// src f32 [b][s=64][d=1024] -> srcT f16 [b][d][64]  (LDS-tiled transpose)
__global__ void transpose_src(const float* __restrict__ src, u16* __restrict__ srcT) {
    __shared__ u16 tile[64][65];
    int b = blockIdx.x >> 4, dt = blockIdx.x & 15;
    int d0 = dt * 64;
    for (int k = threadIdx.x; k < 4096; k += 256) {
        int s = k >> 6, dd = k & 63;
        tile[dd][s] = f2h(src[((size_t)b * 64 + s) * 1024 + d0 + dd]);
    }
    __syncthreads();
    for (int k = threadIdx.x; k < 4096; k += 256) {
        int dd = k >> 6, s = k & 63;
        srcT[((size_t)b * 1024 + d0 + dd) * 64 + s] = tile[dd][s];
    }
}

__global__ void srcbias_k(const float* __restrict__ src, const float* __restrict__ bp,
                          float* __restrict__ sb) {
    int bs = blockIdx.x;
    int tid = threadIdx.x;
    const float4* s4 = (const float4*)(src + (size_t)bs * 1024);
    const float4* b4 = (const float4*)bp;
    float4 a = s4[tid], w = b4[tid];
    float p = a.x * w.x + a.y * w.y + a.z * w.z + a.w * w.w;
    for (int off = 32; off; off >>= 1) p += __shfl_xor(p, off);
    __shared__ float r4[4];
    if ((tid & 63) == 0) r4[tid >> 6] = p;
    __syncthreads();
    if (tid == 0) sb[bs] = r4[0] + r4[1] + r4[2] + r4[3];
}

__global__ void tail_copy(const float* __restrict__ hf, const float* __restrict__ cf,
                          const float* __restrict__ hhf, float* __restrict__ out) {
    int i = blockIdx.x * 256 + threadIdx.x;  // 16384
    out[65536000 + i] = hf[i];
    out[65536000 + 16384 + i] = cf[i];
    out[65536000 + 32768 + i] = hhf[i];
}

// ---------------------------------------------------------------------------
extern "C" void kernel_launch(void* const* d_in, const int* in_sizes, int n_in,
                              void* d_out, int out_size, void* d_ws, size_t ws_size,
                              hipStream_t stream) {
    (void)in_sizes; (void)n_in; (void)out_size; (void)ws_size;
    const float* src = (const float*)d_in[0];
    const int* trg = (const int*)d_in[1];
    const float* emb = (const float*)d_in[2];
    const float* W_ih = (const float*)d_in[3];
    const float* b_ih = (const float*)d_in[4];
    const float* W_hh = (const float*)d_in[5];
    const float* b_hh = (const float*)d_in[6];
    const float* Wp = (const float*)d_in[7];
    const float* bp = (const float*)d_in[8];
    const float* Wah = (const float*)d_in[9];
    const float* bah = (const float*)d_in[10];
    const float* Wfc = (const float*)d_in[11];
    const float* bfc = (const float*)d_in[12];
    const float* iff = (const float*)d_in[13];
    const float* hid = (const float*)d_in[14];
    float* out = (float*)d_out;

    char* wsb = (char*)d_ws;
    size_t off = 0;
    auto alloc = [&](size_t bytes) {
        void* p = wsb + off;
        off += (bytes + 255) & ~(size_t)255;
        return p;
    };
    float* xg2     = (float*)alloc(2048UL * 2048 * 4);   // [t*32+b][2048]
    u16*   srcWp_h = (u16*)  alloc(2048UL * 512 * 2);    // [b*64+s][512] f16
    float* srcbias = (float*)alloc(2048UL * 4);
    u16*   srcT    = (u16*)  alloc(32UL * 1024 * 64 * 2);// [b][d][s] f16
    u16*   Wcat_h  = (u16*)  alloc(2048UL * 1024 * 2);   // f16
    u16*   Wah_h   = (u16*)  alloc(512UL * 1536 * 2);    // f16
    u16*   outs_h  = (u16*)  alloc(2048UL * 512 * 2);    // [t*32+b][512] f16
    u16*   Xemb    = (u16*)  alloc(2048UL * 512 * 2);    // bf16
    u16*   WihX    = (u16*)  alloc(2048UL * 512 * 2);    // bf16
    u16*   WpT     = (u16*)  alloc(512UL * 1024 * 2);    // bf16
    u16*   srcB    = (u16*)  alloc(2048UL * 1024 * 2);   // bf16
    u16*   Wfc_h   = (u16*)  alloc(32000UL * 512 * 2);   // f16
    float* h_last  = (float*)alloc(16384UL * 4);
    float* c_last  = (float*)alloc(16384UL * 4);
    float* hh_last = (float*)alloc(16384UL * 4);

    // prep / conversions
    conv_f2b4<<<2048, 256, 0, stream>>>(src, srcB, 524288);
    conv_f2h4<<<768, 256, 0, stream>>>(Wah, Wah_h, 196608);
    conv_f2h4<<<16000, 256, 0, stream>>>(Wfc, Wfc_h, 4096000);
    conv_wihx<<<1024, 256, 0, stream>>>(W_ih, WihX);
    conv_wcat_h<<<2048, 256, 0, stream>>>(W_ih, W_hh, Wcat_h);
    gather_emb<<<2048, 128, 0, stream>>>(trg, emb, Xemb);
    transpose_wp<<<2048, 256, 0, stream>>>(Wp, WpT);
    transpose_src<<<512, 256, 0, stream>>>(src, srcT);
    srcbias_k<<<2048, 256, 0, stream>>>(src, bp, srcbias);

    // hoisted GEMMs
    gemm_bt<<<dim3(16, 16), 256, 0, stream>>>(Xemb, WihX, xg2, nullptr,
                                              b_ih, b_hh, 2048, 2048, 512, 0);
    gemm_bt<<<dim3(4, 16), 256, 0, stream>>>(srcB, WpT, nullptr, srcWp_h,
                                             nullptr, nullptr, 2048, 512, 1024, 1);

    // whole recurrence: 32 independent blocks (one per batch item), 1 dispatch
    recur_b<<<32, 512, 0, stream>>>(Wcat_h, xg2, srcWp_h, srcbias, srcT,
                                    Wah_h, bah, iff, hid, outs_h,
                                    h_last, c_last, hh_last);

    // final projection (f16 both operands) + states
    gemm_fc<<<dim3(16, 250), 256, 0, stream>>>(outs_h, Wfc_h, out, bfc);
    tail_copy<<<64, 256, 0, stream>>>(h_last, c_last, hh_last, out);
}

// Round 5
// 2067.921 us; speedup vs baseline: 6.8445x; 6.8445x over previous
//
#include <hip/hip_runtime.h>

typedef unsigned short u16;
typedef short bf16x8 __attribute__((ext_vector_type(8)));
typedef float f32x4 __attribute__((ext_vector_type(4)));

struct __align__(8) u16x4s { u16 x, y, z, w; };

__device__ __forceinline__ u16 f2bf(float f) {
    union { float f; unsigned u; } v; v.f = f;
    unsigned u = v.u;
    unsigned r = u + 0x7fffu + ((u >> 16) & 1u);
    return (u16)(r >> 16);
}
__device__ __forceinline__ float bf2f(unsigned b) {
    union { unsigned u; float f; } v; v.u = (b & 0xffffu) << 16;
    return v.f;
}
__device__ __forceinline__ float sigmoidf(float x) { return 1.0f / (1.0f + expf(-x)); }

#define GLOAD_LDS16(g, l) __builtin_amdgcn_global_load_lds( \
    (const __attribute__((address_space(1))) unsigned int*)(g), \
    (__attribute__((address_space(3))) unsigned int*)(l), 16, 0, 0)

// ---------------------------------------------------------------------------
// bf16 GEMM: C(M,N) = A(M,K) * Bt(N,K)^T
// mode 0: xgates -> permuted xg2[t][g][rr][b] layout + b_ih + b_hh
// mode 1: Cb[m*N+n] = bf16(acc)   (srcWp)
// ---------------------------------------------------------------------------
__global__ __launch_bounds__(256) void gemm_bt(
    const u16* __restrict__ A, const u16* __restrict__ Bt,
    float* __restrict__ Cf, u16* __restrict__ Cb,
    const float* __restrict__ bias1, const float* __restrict__ bias2,
    int M, int N, int K, int mode)
{
    __shared__ __align__(16) u16 As[128 * 64];
    __shared__ __align__(16) u16 Bs[128 * 64];
    int tid = threadIdx.x;
    int w = tid >> 6, lane = tid & 63;
    int wm = w >> 1, wn = w & 1;
    int m0 = blockIdx.y * 128, n0 = blockIdx.x * 128;

    f32x4 acc[4][4];
#pragma unroll
    for (int i = 0; i < 4; i++)
#pragma unroll
        for (int j = 0; j < 4; j++)
#pragma unroll
            for (int r = 0; r < 4; r++) acc[i][j][r] = 0.0f;

    int lrow = lane >> 3;
    int lcol = (lane & 7) * 8;

    for (int k0 = 0; k0 < K; k0 += 64) {
#pragma unroll
        for (int i = 0; i < 4; i++) {
            int li = i * 4 + w;
            int row = li * 8 + lrow;
            const u16* ga = A + (size_t)(m0 + row) * K + k0 + lcol;
            const u16* gb = Bt + (size_t)(n0 + row) * K + k0 + lcol;
            GLOAD_LDS16(ga, As + li * 512);
            GLOAD_LDS16(gb, Bs + li * 512);
        }
        __syncthreads();
        int lm = lane & 15;
#pragma unroll
        for (int kk = 0; kk < 2; kk++) {
            int lk = kk * 32 + (lane >> 4) * 8;
            bf16x8 af[4], bfr[4];
#pragma unroll
            for (int mt = 0; mt < 4; mt++)
                af[mt] = *(const bf16x8*)(As + (wm * 64 + mt * 16 + lm) * 64 + lk);
#pragma unroll
            for (int nt = 0; nt < 4; nt++)
                bfr[nt] = *(const bf16x8*)(Bs + (wn * 64 + nt * 16 + lm) * 64 + lk);
#pragma unroll
            for (int mt = 0; mt < 4; mt++)
#pragma unroll
                for (int nt = 0; nt < 4; nt++)
                    acc[mt][nt] = __builtin_amdgcn_mfma_f32_16x16x32_bf16(
                        af[mt], bfr[nt], acc[mt][nt], 0, 0, 0);
        }
        __syncthreads();
    }

    int col = lane & 15, rowq = (lane >> 4) * 4;
#pragma unroll
    for (int mt = 0; mt < 4; mt++) {
#pragma unroll
        for (int nt = 0; nt < 4; nt++) {
            f32x4 v = acc[mt][nt];
            int gn = n0 + wn * 64 + nt * 16 + col;
            int gmb = m0 + wm * 64 + mt * 16 + rowq;
#pragma unroll
            for (int r = 0; r < 4; r++) {
                int gm = gmb + r;
                float val = v[r];
                if (mode == 0) {
                    // gm = t*32+b, gn = gate row = q*512 + g*4 + jl
                    int t = gm >> 5, b = gm & 31;
                    int q = gn >> 9, g = (gn & 511) >> 2, jl = gn & 3;
                    Cf[(((size_t)t * 128 + g) * 16 + q * 4 + jl) * 32 + b] =
                        val + bias1[gn] + bias2[gn];
                } else {
                    Cb[(size_t)gm * N + gn] = f2bf(val);
                }
            }
        }
    }
}

// ---------------------------------------------------------------------------
// FC GEMM: out[(b*64+t)*32000+n] = outs(bf16) @ WfcB(bf16)^T + bfc
// Both operands bf16, staged via global_load_lds. (R1-proven variant.)
// ---------------------------------------------------------------------------
__global__ __launch_bounds__(256) void gemm_fc(
    const u16* __restrict__ A, const u16* __restrict__ Bt,
    float* __restrict__ out, const float* __restrict__ bfc)
{
    __shared__ __align__(16) u16 As[128 * 64];
    __shared__ __align__(16) u16 Bs[128 * 64];
    int tid = threadIdx.x;
    int w = tid >> 6, lane = tid & 63;
    int wm = w >> 1, wn = w & 1;
    int m0 = blockIdx.x * 128, n0 = blockIdx.y * 128;

    f32x4 acc[4][4];
#pragma unroll
    for (int i = 0; i < 4; i++)
#pragma unroll
        for (int j = 0; j < 4; j++)
#pragma unroll
            for (int r = 0; r < 4; r++) acc[i][j][r] = 0.0f;

    int lrow = lane >> 3;
    int lcol = (lane & 7) * 8;

    for (int k0 = 0; k0 < 512; k0 += 64) {
#pragma unroll
        for (int i = 0; i < 4; i++) {
            int li = i * 4 + w;
            int row = li * 8 + lrow;
            GLOAD_LDS16(A + (size_t)(m0 + row) * 512 + k0 + lcol, As + li * 512);
            GLOAD_LDS16(Bt + (size_t)(n0 + row) * 512 + k0 + lcol, Bs + li * 512);
        }
        __syncthreads();
        int lm = lane & 15;
#pragma unroll
        for (int kk = 0; kk < 2; kk++) {
            int lk = kk * 32 + (lane >> 4) * 8;
            bf16x8 af[4], bfr[4];
#pragma unroll
            for (int mt = 0; mt < 4; mt++)
                af[mt] = *(const bf16x8*)(As + (wm * 64 + mt * 16 + lm) * 64 + lk);
#pragma unroll
            for (int nt = 0; nt < 4; nt++)
                bfr[nt] = *(const bf16x8*)(Bs + (wn * 64 + nt * 16 + lm) * 64 + lk);
#pragma unroll
            for (int mt = 0; mt < 4; mt++)
#pragma unroll
                for (int nt = 0; nt < 4; nt++)
                    acc[mt][nt] = __builtin_amdgcn_mfma_f32_16x16x32_bf16(
                        af[mt], bfr[nt], acc[mt][nt], 0, 0, 0);
        }
        __syncthreads();
    }

    int col = lane & 15, rowq = (lane >> 4) * 4;
#pragma unroll
    for (int mt = 0; mt < 4; mt++) {
#pragma unroll
        for (int nt = 0; nt < 4; nt++) {
            f32x4 v = acc[mt][nt];
            int gn = n0 + wn * 64 + nt * 16 + col;
            int gmb = m0 + wm * 64 + mt * 16 + rowq;
#pragma unroll
            for (int r = 0; r < 4; r++) {
                int gm = gmb + r;
                int t = gm >> 5, b = gm & 31;
                out[((size_t)b * 64 + t) * 32000 + gn] = v[r] + bfc[gn];
            }
        }
    }
}

// ---------------------------------------------------------------------------
// Per-step LSTM via MFMA. 128 WGs; WG g owns hidden units g*4..g*4+3
// (16 gate rows). A = Astate[32][1024] bf16 ([hhat|h]), B = Wcat rows,
// both fragments loaded directly from global. k split over 4 waves.
// ---------------------------------------------------------------------------
__global__ __launch_bounds__(256) void lstm_mfma(
    const u16* __restrict__ Wcat, const u16* __restrict__ As_in,
    const float* __restrict__ xg2, float* __restrict__ cbuf,
    float* __restrict__ h_f32, u16* __restrict__ As_out, int t)
{
    __shared__ float red[4][2][16][20];
    int tid = threadIdx.x;
    int w = tid >> 6, lane = tid & 63;
    int g = blockIdx.x;

    f32x4 acc0, acc1;
#pragma unroll
    for (int r = 0; r < 4; r++) { acc0[r] = 0.0f; acc1[r] = 0.0f; }

    int m16 = lane & 15;
    int koff = (lane >> 4) * 8;
    int rr = lane & 15;
    int brow = (rr >> 2) * 512 + g * 4 + (rr & 3);
    const u16* bptr = Wcat + (size_t)brow * 1024 + w * 256 + koff;
    const u16* ap0 = As_in + (size_t)m16 * 1024 + w * 256 + koff;
    const u16* ap1 = As_in + (size_t)(m16 + 16) * 1024 + w * 256 + koff;

#pragma unroll
    for (int kk = 0; kk < 8; kk++) {
        bf16x8 bf = *(const bf16x8*)(bptr + kk * 32);
        bf16x8 a0 = *(const bf16x8*)(ap0 + kk * 32);
        bf16x8 a1 = *(const bf16x8*)(ap1 + kk * 32);
        acc0 = __builtin_amdgcn_mfma_f32_16x16x32_bf16(a0, bf, acc0, 0, 0, 0);
        acc1 = __builtin_amdgcn_mfma_f32_16x16x32_bf16(a1, bf, acc1, 0, 0, 0);
    }
    // C layout: col(lane&15)=B row index rr, rows (lane>>4)*4+r = A row (b local)
    *(f32x4*)&red[w][0][lane & 15][(lane >> 4) * 4] = acc0;
    *(f32x4*)&red[w][1][lane & 15][(lane >> 4) * 4] = acc1;
    __syncthreads();

    if (tid < 128) {
        int b = tid & 31, jl = tid >> 5;
        int mt = b >> 4, ml = b & 15;
        float gv[4];
#pragma unroll
        for (int q = 0; q < 4; q++) {
            int r2 = q * 4 + jl;
            float s = red[0][mt][r2][ml] + red[1][mt][r2][ml]
                    + red[2][mt][r2][ml] + red[3][mt][r2][ml];
            gv[q] = s + xg2[(((size_t)t * 128 + g) * 16 + r2) * 32 + b];
        }
        float ig = sigmoidf(gv[0]);
        float fg = sigmoidf(gv[1]);
        float gg = tanhf(gv[2]);
        float og = sigmoidf(gv[3]);
        int j = g * 4 + jl;
        size_t ci = (size_t)b * 512 + j;
        float cn = fg * cbuf[ci] + ig * gg;
        cbuf[ci] = cn;
        float hv = og * tanhf(cn);
        h_f32[ci] = hv;
        As_out[(size_t)b * 1024 + 512 + j] = f2bf(hv);
    }
}

// ---------------------------------------------------------------------------
// Per-step attention + h_hat. grid (8 q-slices, 32 b). Each WG redundantly
// computes scores/softmax/ctx for its b, then 64 Wah rows.
// Context uses srcT[b][d][s] (contiguous in s; bit-identical sum order).
// ---------------------------------------------------------------------------
__global__ __launch_bounds__(256) void attn_hhat(
    const u16* __restrict__ srcT, const u16* __restrict__ srcWpB,
    const float* __restrict__ srcbias, const float* __restrict__ h_f32,
    const u16* __restrict__ WahB, const float* __restrict__ bah,
    float* __restrict__ hhat_f32, u16* __restrict__ As_out,
    u16* __restrict__ outs, int t)
{
    int q = blockIdx.x;
    int b = blockIdx.y;
    int tid = threadIdx.x;
    __shared__ __align__(16) float cat[1536];
    __shared__ float probs[64];
    __shared__ float red2[256];

    for (int i = tid; i < 512; i += 256) cat[i] = h_f32[(size_t)b * 512 + i];
    __syncthreads();

    {
        int s = tid >> 2, ch = tid & 3;
        const uint4* wp4 = (const uint4*)(srcWpB + ((size_t)b * 64 + s) * 512 + ch * 128);
        const float* hp = cat + ch * 128;
        float p = 0.f;
#pragma unroll 4
        for (int k8 = 0; k8 < 16; k8++) {
            uint4 wv = wp4[k8];
            const float* x = hp + k8 * 8;
            p += bf2f(wv.x) * x[0] + bf2f(wv.x >> 16) * x[1];
            p += bf2f(wv.y) * x[2] + bf2f(wv.y >> 16) * x[3];
            p += bf2f(wv.z) * x[4] + bf2f(wv.z >> 16) * x[5];
            p += bf2f(wv.w) * x[6] + bf2f(wv.w >> 16) * x[7];
        }
        red2[tid] = p;
    }
    __syncthreads();
    if (tid < 64) {
        float sc = (red2[tid * 4] + red2[tid * 4 + 1] + red2[tid * 4 + 2] + red2[tid * 4 + 3]
                    + srcbias[b * 64 + tid]) * 0.04419417382415922f;
        float m = sc;
        for (int off = 32; off; off >>= 1) m = fmaxf(m, __shfl_xor(m, off));
        float e = expf(sc - m);
        float sum = e;
        for (int off = 32; off; off >>= 1) sum += __shfl_xor(sum, off);
        probs[tid] = e / sum;
    }
    __syncthreads();

#pragma unroll
    for (int it = 0; it < 4; it++) {
        int d = it * 256 + tid;
        const u16* sp = srcT + ((size_t)b * 1024 + d) * 64;
        float a = 0.f;
#pragma unroll
        for (int u = 0; u < 8; u++) {
            uint4 sv = *(const uint4*)(sp + u * 8);
            const float* pp = probs + u * 8;
            a += bf2f(sv.x) * pp[0] + bf2f(sv.x >> 16) * pp[1];
            a += bf2f(sv.y) * pp[2] + bf2f(sv.y >> 16) * pp[3];
            a += bf2f(sv.z) * pp[4] + bf2f(sv.z >> 16) * pp[5];
            a += bf2f(sv.w) * pp[6] + bf2f(sv.w >> 16) * pp[7];
        }
        cat[512 + d] = a;
    }
    __syncthreads();

    int jj = tid >> 2, part = tid & 3;
    int j = q * 64 + jj;
    const uint4* w8 = (const uint4*)(WahB + (size_t)j * 1536 + part * 384);
    const float* xv = cat + part * 384;
    float a0 = 0.f, a1 = 0.f, a2 = 0.f, a3 = 0.f;
#pragma unroll 4
    for (int k8 = 0; k8 < 48; k8++) {
        uint4 wv = w8[k8];
        const float* x = xv + k8 * 8;
        a0 += bf2f(wv.x) * x[0] + bf2f(wv.x >> 16) * x[1];
        a1 += bf2f(wv.y) * x[2] + bf2f(wv.y >> 16) * x[3];
        a2 += bf2f(wv.z) * x[4] + bf2f(wv.z >> 16) * x[5];
        a3 += bf2f(wv.w) * x[6] + bf2f(wv.w >> 16) * x[7];
    }
    float a = (a0 + a1) + (a2 + a3);
    a += __shfl_xor(a, 1);
    a += __shfl_xor(a, 2);
    if (part == 0) {
        float v = tanhf(a + bah[j]);
        hhat_f32[(size_t)b * 512 + j] = v;
        As_out[(size_t)b * 1024 + j] = f2bf(v);
        outs[((size_t)t * 32 + b) * 512 + j] = f2bf(v);
    }
}

// ---------------------------------------------------------------------------
// Prep kernels
// ---------------------------------------------------------------------------
__global__ void conv_f2b4(const float* __restrict__ in, u16* __restrict__ out, int n4) {
    int i = blockIdx.x * 256 + threadIdx.x;
    if (i < n4) {
        float4 v = ((const float4*)in)[i];
        u16x4s o; o.x = f2bf(v.x); o.y = f2bf(v.y); o.z = f2bf(v.z); o.w = f2bf(v.w);
        *(u16x4s*)(out + (size_t)i * 4) = o;
    }
}

__global__ void conv_wihx(const float* __restrict__ W_ih, u16* __restrict__ out) {
    int i = blockIdx.x * 256 + threadIdx.x;  // 2048 rows * 128 float4
    int r = i >> 7, k4 = i & 127;
    float4 v = ((const float4*)(W_ih + (size_t)r * 1024))[k4];
    u16x4s o; o.x = f2bf(v.x); o.y = f2bf(v.y); o.z = f2bf(v.z); o.w = f2bf(v.w);
    *(u16x4s*)(out + (size_t)r * 512 + k4 * 4) = o;
}

__global__ void conv_wcat(const float* __restrict__ W_ih, const float* __restrict__ W_hh,
                          u16* __restrict__ Wcat) {
    int i = blockIdx.x * 256 + threadIdx.x;  // 2048 * 256
    int r = i >> 8, c4 = i & 255;
    int col = c4 * 4;
    const float* src = (col < 512) ? (W_ih + (size_t)r * 1024 + 512 + col)
                                   : (W_hh + (size_t)r * 512 + (col - 512));
    float4 v = *(const float4*)src;
    u16x4s o; o.x = f2bf(v.x); o.y = f2bf(v.y); o.z = f2bf(v.z); o.w = f2bf(v.w);
    *(u16x4s*)(Wcat + (size_t)r * 1024 + col) = o;
}

__global__ void gather_emb(const int* __restrict__ trg, const float* __restrict__ emb,
                           u16* __restrict__ X) {
    int m = blockIdx.x;  // t*32+b
    int t = m >> 5, b = m & 31;
    int v = trg[b * 64 + t];
    const float4* e4 = (const float4*)(emb + (size_t)v * 512);
    int tid = threadIdx.x;  // 128
    float4 x = e4[tid];
    u16x4s o; o.x = f2bf(x.x); o.y = f2bf(x.y); o.z = f2bf(x.z); o.w = f2bf(x.w);
    *(u16x4s*)(X + (size_t)m * 512 + tid * 4) = o;
}

__global__ void transpose_wp(const float* __restrict__ Wp, u16* __restrict__ WpT) {
    int i = blockIdx.x * 256 + threadIdx.x;  // 512*1024
    int k = i >> 10, d = i & 1023;
    WpT[i] = f2bf(Wp[(size_t)d * 512 + k]);
}

// src f32 [b][s=64][d=1024] -> srcT bf16 [b][d][64]
__global__ void transpose_srcb(const float* __restrict__ src, u16* __restrict__ srcT) {
    __shared__ u16 tile[64][65];
    int b = blockIdx.x >> 4, dt = blockIdx.x & 15;
    int d0 = dt * 64;
    for (int k = threadIdx.x; k < 4096; k += 256) {
        int s = k >> 6, dd = k & 63;
        tile[dd][s] = f2bf(src[((size_t)b * 64 + s) * 1024 + d0 + dd]);
    }
    __syncthreads();
    for (int k = threadIdx.x; k < 4096; k += 256) {
        int dd = k >> 6, s = k & 63;
        srcT[((size_t)b * 1024 + d0 + dd) * 64 + s] = tile[dd][s];
    }
}

__global__ void srcbias_k(const float* __restrict__ src, const float* __restrict__ bp,
                          float* __restrict__ sb) {
    int bs = blockIdx.x;
    int tid = threadIdx.x;
    const float4* s4 = (const float4*)(src + (size_t)bs * 1024);
    const float4* b4 = (const float4*)bp;
    float4 a = s4[tid], w = b4[tid];
    float p = a.x * w.x + a.y * w.y + a.z * w.z + a.w * w.w;
    for (int off = 32; off; off >>= 1) p += __shfl_xor(p, off);
    __shared__ float r4[4];
    if ((tid & 63) == 0) r4[tid >> 6] = p;
    __syncthreads();
    if (tid == 0) sb[bs] = r4[0] + r4[1] + r4[2] + r4[3];
}

__global__ void init_state2(const float* __restrict__ hid, const float* __restrict__ iff,
                            u16* __restrict__ As0, float* __restrict__ c0) {
    int i = blockIdx.x * 256 + threadIdx.x;  // 32768
    int k = i & 1023;
    As0[i] = f2bf(k < 512 ? iff[k] : hid[k - 512]);
    if (i < 16384) c0[i] = hid[512 + (i & 511)];
}

__global__ void tail_copy(const float* __restrict__ hf, const float* __restrict__ cf,
                          const float* __restrict__ hhf, float* __restrict__ out) {
    int i = blockIdx.x * 256 + threadIdx.x;  // 16384
    out[65536000 + i] = hf[i];
    out[65536000 + 16384 + i] = cf[i];
    out[65536000 + 32768 + i] = hhf[i];
}

// ---------------------------------------------------------------------------
extern "C" void kernel_launch(void* const* d_in, const int* in_sizes, int n_in,
                              void* d_out, int out_size, void* d_ws, size_t ws_size,
                              hipStream_t stream) {
    (void)in_sizes; (void)n_in; (void)out_size; (void)ws_size;
    const float* src = (const float*)d_in[0];
    const int* trg = (const int*)d_in[1];
    const float* emb = (const float*)d_in[2];
    const float* W_ih = (const float*)d_in[3];
    const float* b_ih = (const float*)d_in[4];
    const float* W_hh = (const float*)d_in[5];
    const float* b_hh = (const float*)d_in[6];
    const float* Wp = (const float*)d_in[7];
    const float* bp = (const float*)d_in[8];
    const float* Wah = (const float*)d_in[9];
    const float* bah = (const float*)d_in[10];
    const float* Wfc = (const float*)d_in[11];
    const float* bfc = (const float*)d_in[12];
    const float* iff = (const float*)d_in[13];
    const float* hid = (const float*)d_in[14];
    float* out = (float*)d_out;

    char* wsb = (char*)d_ws;
    size_t off = 0;
    auto alloc = [&](size_t bytes) {
        void* p = wsb + off;
        off += (bytes + 255) & ~(size_t)255;
        return p;
    };
    float* xg2     = (float*)alloc(2048UL * 2048 * 4);   // [t][g][rr][b]
    u16*   srcWpB  = (u16*)  alloc(2048UL * 512 * 2);    // [b*64+s][512]
    float* srcbias = (float*)alloc(2048UL * 4);
    float* cbuf    = (float*)alloc(16384UL * 4);
    float* h_f32   = (float*)alloc(16384UL * 4);
    float* hh_f32  = (float*)alloc(16384UL * 4);
    u16*   A0      = (u16*)  alloc(32UL * 1024 * 2);     // state [hhat|h] bf16
    u16*   A1      = (u16*)  alloc(32UL * 1024 * 2);
    u16*   outsB   = (u16*)  alloc(2048UL * 512 * 2);    // [t*32+b][512]
    u16*   Xemb    = (u16*)  alloc(2048UL * 512 * 2);
    u16*   WihX    = (u16*)  alloc(2048UL * 512 * 2);
    u16*   Wcat    = (u16*)  alloc(2048UL * 1024 * 2);   // [hhat-part | W_hh]
    u16*   WpT     = (u16*)  alloc(512UL * 1024 * 2);
    u16*   srcB    = (u16*)  alloc(2048UL * 1024 * 2);
    u16*   srcT    = (u16*)  alloc(32UL * 1024 * 64 * 2);// [b][d][s] bf16
    u16*   WahB    = (u16*)  alloc(512UL * 1536 * 2);
    u16*   WfcB    = (u16*)  alloc(32000UL * 512 * 2);   // bf16 Wfc

    // prep / conversions
    conv_f2b4<<<2048, 256, 0, stream>>>(src, srcB, 524288);
    conv_f2b4<<<768, 256, 0, stream>>>(Wah, WahB, 196608);
    conv_f2b4<<<16000, 256, 0, stream>>>(Wfc, WfcB, 4096000);
    conv_wihx<<<1024, 256, 0, stream>>>(W_ih, WihX);
    conv_wcat<<<2048, 256, 0, stream>>>(W_ih, W_hh, Wcat);
    gather_emb<<<2048, 128, 0, stream>>>(trg, emb, Xemb);
    transpose_wp<<<2048, 256, 0, stream>>>(Wp, WpT);
    transpose_srcb<<<512, 256, 0, stream>>>(src, srcT);
    srcbias_k<<<2048, 256, 0, stream>>>(src, bp, srcbias);
    init_state2<<<128, 256, 0, stream>>>(hid, iff, A0, cbuf);

    // hoisted GEMMs
    gemm_bt<<<dim3(16, 16), 256, 0, stream>>>(Xemb, WihX, xg2, nullptr,
                                              b_ih, b_hh, 2048, 2048, 512, 0);
    gemm_bt<<<dim3(4, 16), 256, 0, stream>>>(srcB, WpT, nullptr, srcWpB,
                                             nullptr, nullptr, 2048, 512, 1024, 1);

    // sequential recurrence (ping-pong state buffers)
    u16* Ab[2] = {A0, A1};
    for (int t = 0; t < 64; t++) {
        u16* Ain = Ab[t & 1];
        u16* Aout = Ab[(t + 1) & 1];
        lstm_mfma<<<128, 256, 0, stream>>>(Wcat, Ain, xg2, cbuf, h_f32, Aout, t);
        attn_hhat<<<dim3(8, 32), 256, 0, stream>>>(srcT, srcWpB, srcbias, h_f32,
                                                   WahB, bah, hh_f32, Aout, outsB, t);
    }

    // final projection (bf16 Wfc via global_load_lds) + states
    gemm_fc<<<dim3(16, 250), 256, 0, stream>>>(outsB, WfcB, out, bfc);
    tail_copy<<<64, 256, 0, stream>>>(h_f32, cbuf, hh_f32, out);
}